// Round 6
// baseline (165.214 us; speedup 1.0000x reference)
//
#include <hip/hip_runtime.h>

// RgbNet: fused hash-grid encode (5 samples/ray, 6 levels) + MLP 120->64->64->64->3.
// Cost model (per CU = 64 rays): gather = 15360 scattered float4, ~L3 latency, bound by
// outstanding-loads -> want 16 waves AND clustered load issue; MLP = DS-issue bound when
// many waves redundantly stream acts -> want FEW fat waves (4 waves x 16 neurons).
// R6: 256 blocks x 1024 thr (64 rays, 16 waves), launch_bounds(1024) only (VGPR<=128).
//   Phase 0 (all 16 waves): per lane batch-compute 16 corner ptrs+weights, issue all 16
//     loads clustered (2x in-flight vs R2), combine -> sFeat[k][64] col-major.
//   Phase 1-3 (waves 0-3 only): wave owns 16 neurons; weights wave-uniform via
//     readfirstlane -> s_load_dwordx4 chunks; acts 4x b32 (st64-mergeable); 64 FMA/chunk,
//     16 independent acc chains. Other waves idle at barriers (no issue cost).
//   Phase 4 (waves 0-2): one output channel each.
// LDS: sFeat 120x64 (30720B) + sHa 64x64 + sHb 64x64 = 63488B; L3 output reuses sHa.

#define NSAMP 300
#define HSIZE (1u << 19)

__global__ __launch_bounds__(1024) void rgbnet_fused(
    const float4* __restrict__ x,       // [N] rows: sx,sy,ex,ey
    const int*    __restrict__ idxf,    // [N]
    const float4* __restrict__ emb,     // [6 * 2^19] float4 entries
    const float* __restrict__ W1, const float* __restrict__ b1,
    const float* __restrict__ W2, const float* __restrict__ b2,
    const float* __restrict__ W3, const float* __restrict__ b3,
    const float* __restrict__ W4, const float* __restrict__ b4,
    float* __restrict__ out, int N)
{
    __shared__ float sFeat[120 * 64];
    __shared__ float sHa[64 * 64];
    __shared__ float sHb[64 * 64];

    const int tid = threadIdx.x;
    const int r   = tid & 63;            // local ray (= lane)
    const int w   = tid >> 6;            // wave id 0..15
    const int ray = blockIdx.x * 64 + r;

    // ---------------- Phase 0: grid encoding, batched issue ----------------
    {
        const float4 xr = x[ray];
        const int    i0 = idxf[ray];
        const int have2 = (w < 14);      // pairs: w and (if w<14) w+16

        const float4* ptr0[8]; const float4* ptr1[8];
        float cw0[8], cw1[8];

        #pragma unroll
        for (int a = 0; a < 2; ++a) {
            const int p = w + a * 16;
            if (a == 1 && !have2) break;
            const int d = p / 6;
            const int l = p - d * 6;
            int s = i0 + d - 2;
            s = max(0, min(s, NSAMP - 1));
            const float t   = (float)s * (1.0f / 299.0f);
            const float omt = 1.0f - t;
            const int   R   = 4 << l;
            const float fR  = (float)R;
            const float px = (xr.x * omt + xr.z * t) * fR;
            const float py = (xr.y * omt + xr.w * t) * fR;
            const float pz = t * fR;
            const float fx0 = floorf(px), fy0 = floorf(py), fz0 = floorf(pz);
            const float wx = px - fx0, wy = py - fy0, wz = pz - fz0;
            const int ix = (int)fx0, iy = (int)fy0, iz = (int)fz0;
            const int Rp1 = R + 1;
            const float4* __restrict__ ebase = emb + (size_t)l * HSIZE;
            #pragma unroll
            for (int c = 0; c < 8; ++c) {
                const int ox = (c >> 2) & 1, oy = (c >> 1) & 1, oz = c & 1;
                int cx = min(ix + ox, R); cx = max(cx, 0);
                int cy = min(iy + oy, R); cy = max(cy, 0);
                int cz = min(iz + oz, R); cz = max(cz, 0);
                unsigned idx;
                if (l < 5) {
                    idx = (unsigned)(cx + cy * Rp1 + cz * Rp1 * Rp1);
                } else {
                    idx = ((unsigned)cx * 1u
                         ^ (unsigned)cy * 2654435761u
                         ^ (unsigned)cz * 805459861u) & (HSIZE - 1u);
                }
                const float cw = (ox ? wx : 1.f - wx)
                               * (oy ? wy : 1.f - wy)
                               * (oz ? wz : 1.f - wz);
                if (a == 0) { ptr0[c] = ebase + idx; cw0[c] = cw; }
                else        { ptr1[c] = ebase + idx; cw1[c] = cw; }
            }
        }

        // issue all loads clustered
        float4 e0[8], e1[8];
        #pragma unroll
        for (int c = 0; c < 8; ++c) e0[c] = *ptr0[c];
        if (have2) {
            #pragma unroll
            for (int c = 0; c < 8; ++c) e1[c] = *ptr1[c];
        }

        // combine + store
        {
            float ax = 0.f, ay = 0.f, az = 0.f, aw = 0.f;
            #pragma unroll
            for (int c = 0; c < 8; ++c) {
                ax = fmaf(cw0[c], e0[c].x, ax);
                ay = fmaf(cw0[c], e0[c].y, ay);
                az = fmaf(cw0[c], e0[c].z, az);
                aw = fmaf(cw0[c], e0[c].w, aw);
            }
            const int k0 = w * 4;
            sFeat[(k0 + 0) * 64 + r] = ax;
            sFeat[(k0 + 1) * 64 + r] = ay;
            sFeat[(k0 + 2) * 64 + r] = az;
            sFeat[(k0 + 3) * 64 + r] = aw;
        }
        if (have2) {
            float ax = 0.f, ay = 0.f, az = 0.f, aw = 0.f;
            #pragma unroll
            for (int c = 0; c < 8; ++c) {
                ax = fmaf(cw1[c], e1[c].x, ax);
                ay = fmaf(cw1[c], e1[c].y, ay);
                az = fmaf(cw1[c], e1[c].z, az);
                aw = fmaf(cw1[c], e1[c].w, aw);
            }
            const int k0 = (w + 16) * 4;
            sFeat[(k0 + 0) * 64 + r] = ax;
            sFeat[(k0 + 1) * 64 + r] = ay;
            sFeat[(k0 + 2) * 64 + r] = az;
            sFeat[(k0 + 3) * 64 + r] = aw;
        }
    }
    __syncthreads();

    const int wu = __builtin_amdgcn_readfirstlane(w);  // uniform wave id -> s_load weights
    const int j0 = wu * 16;                            // MLP waves own 16 neurons

    float acc[16];

    // ---------------- Layer 1: 120 -> 64 (waves 0-3) ----------------
    if (wu < 4) {
        #pragma unroll
        for (int jj = 0; jj < 16; ++jj) acc[jj] = b1[j0 + jj];
        for (int kc = 0; kc < 120; kc += 4) {
            float a0 = sFeat[(kc + 0) * 64 + r];
            float a1 = sFeat[(kc + 1) * 64 + r];
            float a2 = sFeat[(kc + 2) * 64 + r];
            float a3 = sFeat[(kc + 3) * 64 + r];
            #pragma unroll
            for (int jj = 0; jj < 16; ++jj) {
                const float* wr = &W1[(j0 + jj) * 120 + kc];
                acc[jj] = fmaf(a0, wr[0], acc[jj]);
                acc[jj] = fmaf(a1, wr[1], acc[jj]);
                acc[jj] = fmaf(a2, wr[2], acc[jj]);
                acc[jj] = fmaf(a3, wr[3], acc[jj]);
            }
        }
        #pragma unroll
        for (int jj = 0; jj < 16; ++jj)
            sHa[(j0 + jj) * 64 + r] = fmaxf(acc[jj], 0.f);
    }
    __syncthreads();

    // ---------------- Layer 2: 64 -> 64 (waves 0-3) ----------------
    if (wu < 4) {
        #pragma unroll
        for (int jj = 0; jj < 16; ++jj) acc[jj] = b2[j0 + jj];
        for (int kc = 0; kc < 64; kc += 4) {
            float a0 = sHa[(kc + 0) * 64 + r];
            float a1 = sHa[(kc + 1) * 64 + r];
            float a2 = sHa[(kc + 2) * 64 + r];
            float a3 = sHa[(kc + 3) * 64 + r];
            #pragma unroll
            for (int jj = 0; jj < 16; ++jj) {
                const float* wr = &W2[(j0 + jj) * 64 + kc];
                acc[jj] = fmaf(a0, wr[0], acc[jj]);
                acc[jj] = fmaf(a1, wr[1], acc[jj]);
                acc[jj] = fmaf(a2, wr[2], acc[jj]);
                acc[jj] = fmaf(a3, wr[3], acc[jj]);
            }
        }
        #pragma unroll
        for (int jj = 0; jj < 16; ++jj)
            sHb[(j0 + jj) * 64 + r] = fmaxf(acc[jj], 0.f);
    }
    __syncthreads();

    // ---------------- Layer 3: 64 -> 64 (waves 0-3), writes into sHa ----------------
    if (wu < 4) {
        #pragma unroll
        for (int jj = 0; jj < 16; ++jj) acc[jj] = b3[j0 + jj];
        for (int kc = 0; kc < 64; kc += 4) {
            float a0 = sHb[(kc + 0) * 64 + r];
            float a1 = sHb[(kc + 1) * 64 + r];
            float a2 = sHb[(kc + 2) * 64 + r];
            float a3 = sHb[(kc + 3) * 64 + r];
            #pragma unroll
            for (int jj = 0; jj < 16; ++jj) {
                const float* wr = &W3[(j0 + jj) * 64 + kc];
                acc[jj] = fmaf(a0, wr[0], acc[jj]);
                acc[jj] = fmaf(a1, wr[1], acc[jj]);
                acc[jj] = fmaf(a2, wr[2], acc[jj]);
                acc[jj] = fmaf(a3, wr[3], acc[jj]);
            }
        }
        #pragma unroll
        for (int jj = 0; jj < 16; ++jj)
            sHa[(j0 + jj) * 64 + r] = fmaxf(acc[jj], 0.f);   // sHa (L1 out) is dead here
    }
    __syncthreads();

    // ---------------- Output: 64 -> 3 (waves 0-2) ----------------
    if (wu < 3) {
        float o = b4[wu];
        for (int kc = 0; kc < 64; kc += 4) {
            const float* wr = &W4[wu * 64 + kc];
            o = fmaf(sHa[(kc + 0) * 64 + r], wr[0], o);
            o = fmaf(sHa[(kc + 1) * 64 + r], wr[1], o);
            o = fmaf(sHa[(kc + 2) * 64 + r], wr[2], o);
            o = fmaf(sHa[(kc + 3) * 64 + r], wr[3], o);
        }
        out[(size_t)ray * 3 + wu] = o;
    }
}

extern "C" void kernel_launch(void* const* d_in, const int* in_sizes, int n_in,
                              void* d_out, int out_size, void* d_ws, size_t ws_size,
                              hipStream_t stream) {
    const float4* x    = (const float4*)d_in[0];
    const int*    idxf = (const int*)   d_in[1];
    const float4* emb  = (const float4*)d_in[2];
    const float*  W1   = (const float*) d_in[3];
    const float*  b1   = (const float*) d_in[4];
    const float*  W2   = (const float*) d_in[5];
    const float*  b2   = (const float*) d_in[6];
    const float*  W3   = (const float*) d_in[7];
    const float*  b3   = (const float*) d_in[8];
    const float*  W4   = (const float*) d_in[9];
    const float*  b4   = (const float*) d_in[10];
    float* out = (float*)d_out;

    const int N = in_sizes[0] / 4;              // 16384 rays (x is [N,4])
    const int blocks = (N + 63) / 64;           // 256 blocks of 1024 threads
    hipLaunchKernelGGL(rgbnet_fused, dim3(blocks), dim3(1024), 0, stream,
                       x, idxf, emb, W1, b1, W2, b2, W3, b3, W4, b4, out, N);
}

// Round 7
// 140.364 us; speedup vs baseline: 1.1770x; 1.1770x over previous
//
#include <hip/hip_runtime.h>

// RgbNet: fused hash-grid encode (5 samples/ray, 6 levels) + MLP 120->64->64->64->3.
// R6 lesson: manual pointer-array batching -> VGPR demotion (48) -> serialized gather. Let
// the compiler schedule the simple 8-load cluster (R2 style, ~88 VGPR).
// R5 lesson: (512,6) VGPR cap=36 killed ILP; use (512,4) -> VGPR<=128.
// R7: 512 blocks x 512 thr (32 rays, 8 waves), LDS 24KB -> 2 co-resident blocks/CU:
//   one block's MLP/barriers overlap the other's gather latency tail.
//   Acts row-major [ray][k], rows padded to 31/17 float4 (bank-group conflict-free):
//   ds_read_b128 cuts MLP DS instruction count 4x vs b32 streams (DS pipe was the MLP bound).
// Lane map: r = lane&31 (ray), half = lane>>5, unit u = 2w+half (0..15).
//   Phase 0: unit u gathers pairs {u, u+16} -> sFeat[r][p*4..p*4+3] (one b128 write).
//   Phase 1-3: unit u owns neurons [4u,4u+4); weights per-lane VMEM float4 (L1 broadcast);
//   acts b128 from LDS rows. Phase 4: units 0..2 -> output channels.

#define NSAMP 300
#define HSIZE (1u << 19)
#define RAYS 32
#define FSTRIDE 124   // 31 float4
#define HSTRIDE 68    // 17 float4

__global__ __launch_bounds__(512, 4) void rgbnet_fused(
    const float4* __restrict__ x,       // [N] rows: sx,sy,ex,ey
    const int*    __restrict__ idxf,    // [N]
    const float4* __restrict__ emb,     // [6 * 2^19] float4 entries
    const float* __restrict__ W1, const float* __restrict__ b1,
    const float* __restrict__ W2, const float* __restrict__ b2,
    const float* __restrict__ W3, const float* __restrict__ b3,
    const float* __restrict__ W4, const float* __restrict__ b4,
    float* __restrict__ out, int N)
{
    __shared__ float sm[RAYS * FSTRIDE + RAYS * HSTRIDE];  // 24576 B
    float* sFeat = sm;                   // [32][124]
    float* sHa   = sm + RAYS * FSTRIDE;  // [32][68]
    float* sHb   = sm;                   // [32][68], aliases sFeat (dead after Layer 1)

    const int tid  = threadIdx.x;
    const int lane = tid & 63;
    const int r    = lane & 31;          // local ray
    const int half = lane >> 5;
    const int w    = tid >> 6;           // wave 0..7
    const int u    = w * 2 + half;       // unit 0..15
    const int ray  = blockIdx.x * RAYS + r;

    // ---------------- Phase 0: grid encoding ----------------
    {
        const float4 xr = x[ray];
        const int    i0 = idxf[ray];

        for (int p = u; p < 30; p += 16) {     // unit's pairs: {u, u+16}
            const int d = p / 6;               // gather offset index 0..4 (d-2 in ref)
            const int l = p - d * 6;           // level 0..5
            int s = i0 + d - 2;
            s = max(0, min(s, NSAMP - 1));
            const float t   = (float)s * (1.0f / 299.0f);
            const float omt = 1.0f - t;
            const int   R   = 4 << l;
            const float fR  = (float)R;
            const float px = (xr.x * omt + xr.z * t) * fR;
            const float py = (xr.y * omt + xr.w * t) * fR;
            const float pz = t * fR;
            const float fx0 = floorf(px), fy0 = floorf(py), fz0 = floorf(pz);
            const float wx = px - fx0, wy = py - fy0, wz = pz - fz0;
            const int ix = (int)fx0, iy = (int)fy0, iz = (int)fz0;
            const int Rp1 = R + 1;
            const float4* __restrict__ ebase = emb + (size_t)l * HSIZE;

            float ax = 0.f, ay = 0.f, az = 0.f, aw = 0.f;
            #pragma unroll
            for (int c = 0; c < 8; ++c) {
                const int ox = (c >> 2) & 1, oy = (c >> 1) & 1, oz = c & 1;
                int cx = min(ix + ox, R); cx = max(cx, 0);
                int cy = min(iy + oy, R); cy = max(cy, 0);
                int cz = min(iz + oz, R); cz = max(cz, 0);
                unsigned idx;
                if (l < 5) {
                    idx = (unsigned)(cx + cy * Rp1 + cz * Rp1 * Rp1);   // dense level
                } else {
                    idx = ((unsigned)cx * 1u
                         ^ (unsigned)cy * 2654435761u
                         ^ (unsigned)cz * 805459861u) & (HSIZE - 1u);   // hashed level
                }
                const float4 e = ebase[idx];
                const float cw = (ox ? wx : 1.f - wx)
                               * (oy ? wy : 1.f - wy)
                               * (oz ? wz : 1.f - wz);
                ax = fmaf(cw, e.x, ax);
                ay = fmaf(cw, e.y, ay);
                az = fmaf(cw, e.z, az);
                aw = fmaf(cw, e.w, aw);
            }
            // k0 = p*4 matches ref concat order (d-major, then level, then dim)
            *(float4*)&sFeat[r * FSTRIDE + p * 4] = make_float4(ax, ay, az, aw);
        }
    }
    __syncthreads();

    const int j0 = u * 4;                // unit owns neurons j0..j0+3
    float hh[4];

    // ---------------- Layer 1: 120 -> 64 ----------------
    {
        const float4 bv = *(const float4*)&b1[j0];
        hh[0] = bv.x; hh[1] = bv.y; hh[2] = bv.z; hh[3] = bv.w;
    }
    #pragma unroll 2
    for (int kc = 0; kc < 120; kc += 4) {
        const float4 f = *(const float4*)&sFeat[r * FSTRIDE + kc];
        #pragma unroll
        for (int jj = 0; jj < 4; ++jj) {
            const float4 wv = *(const float4*)&W1[(j0 + jj) * 120 + kc];
            hh[jj] = fmaf(f.x, wv.x, hh[jj]);
            hh[jj] = fmaf(f.y, wv.y, hh[jj]);
            hh[jj] = fmaf(f.z, wv.z, hh[jj]);
            hh[jj] = fmaf(f.w, wv.w, hh[jj]);
        }
    }
    {
        float4 o;
        o.x = fmaxf(hh[0], 0.f); o.y = fmaxf(hh[1], 0.f);
        o.z = fmaxf(hh[2], 0.f); o.w = fmaxf(hh[3], 0.f);
        *(float4*)&sHa[r * HSTRIDE + j0] = o;
    }
    __syncthreads();

    // ---------------- Layer 2: 64 -> 64 ----------------
    // sFeat is dead past the barrier above -> sHb(=sFeat space) writable this phase.
    {
        const float4 bv = *(const float4*)&b2[j0];
        hh[0] = bv.x; hh[1] = bv.y; hh[2] = bv.z; hh[3] = bv.w;
    }
    #pragma unroll 2
    for (int kc = 0; kc < 64; kc += 4) {
        const float4 f = *(const float4*)&sHa[r * HSTRIDE + kc];
        #pragma unroll
        for (int jj = 0; jj < 4; ++jj) {
            const float4 wv = *(const float4*)&W2[(j0 + jj) * 64 + kc];
            hh[jj] = fmaf(f.x, wv.x, hh[jj]);
            hh[jj] = fmaf(f.y, wv.y, hh[jj]);
            hh[jj] = fmaf(f.z, wv.z, hh[jj]);
            hh[jj] = fmaf(f.w, wv.w, hh[jj]);
        }
    }
    {
        float4 o;
        o.x = fmaxf(hh[0], 0.f); o.y = fmaxf(hh[1], 0.f);
        o.z = fmaxf(hh[2], 0.f); o.w = fmaxf(hh[3], 0.f);
        *(float4*)&sHb[r * HSTRIDE + j0] = o;
    }
    __syncthreads();

    // ---------------- Layer 3: 64 -> 64 ----------------
    {
        const float4 bv = *(const float4*)&b3[j0];
        hh[0] = bv.x; hh[1] = bv.y; hh[2] = bv.z; hh[3] = bv.w;
    }
    #pragma unroll 2
    for (int kc = 0; kc < 64; kc += 4) {
        const float4 f = *(const float4*)&sHb[r * HSTRIDE + kc];
        #pragma unroll
        for (int jj = 0; jj < 4; ++jj) {
            const float4 wv = *(const float4*)&W3[(j0 + jj) * 64 + kc];
            hh[jj] = fmaf(f.x, wv.x, hh[jj]);
            hh[jj] = fmaf(f.y, wv.y, hh[jj]);
            hh[jj] = fmaf(f.z, wv.z, hh[jj]);
            hh[jj] = fmaf(f.w, wv.w, hh[jj]);
        }
    }
    {
        float4 o;
        o.x = fmaxf(hh[0], 0.f); o.y = fmaxf(hh[1], 0.f);
        o.z = fmaxf(hh[2], 0.f); o.w = fmaxf(hh[3], 0.f);
        *(float4*)&sHa[r * HSTRIDE + j0] = o;   // sHa (L1 acts) dead after L2 barrier
    }
    __syncthreads();

    // ---------------- Output: 64 -> 3 (units 0..2) ----------------
    if (u < 3) {
        float acc = b4[u];
        #pragma unroll 2
        for (int kc = 0; kc < 64; kc += 4) {
            const float4 f  = *(const float4*)&sHa[r * HSTRIDE + kc];
            const float4 wv = *(const float4*)&W4[u * 64 + kc];
            acc = fmaf(f.x, wv.x, acc);
            acc = fmaf(f.y, wv.y, acc);
            acc = fmaf(f.z, wv.z, acc);
            acc = fmaf(f.w, wv.w, acc);
        }
        out[(size_t)ray * 3 + u] = acc;
    }
}

extern "C" void kernel_launch(void* const* d_in, const int* in_sizes, int n_in,
                              void* d_out, int out_size, void* d_ws, size_t ws_size,
                              hipStream_t stream) {
    const float4* x    = (const float4*)d_in[0];
    const int*    idxf = (const int*)   d_in[1];
    const float4* emb  = (const float4*)d_in[2];
    const float*  W1   = (const float*) d_in[3];
    const float*  b1   = (const float*) d_in[4];
    const float*  W2   = (const float*) d_in[5];
    const float*  b2   = (const float*) d_in[6];
    const float*  W3   = (const float*) d_in[7];
    const float*  b3   = (const float*) d_in[8];
    const float*  W4   = (const float*) d_in[9];
    const float*  b4   = (const float*) d_in[10];
    float* out = (float*)d_out;

    const int N = in_sizes[0] / 4;              // 16384 rays (x is [N,4])
    const int blocks = (N + RAYS - 1) / RAYS;   // 512 blocks of 512 threads
    hipLaunchKernelGGL(rgbnet_fused, dim3(blocks), dim3(512), 0, stream,
                       x, idxf, emb, W1, b1, W2, b2, W3, b3, W4, b4, out, N);
}